// Round 17
// baseline (363.941 us; speedup 1.0000x reference)
//
#include <hip/hip_runtime.h>
#include <cstdint>
#include <cstddef>

// MHA: out = softmax_causal((XqWq^T+bq)(XkWk^T+bk)^T / 8) (XvWv^T+bv) Wo^T + bo
// B=4 S=2048 D=1024 H=16 dk=64. bf16 MFMA, fp32 accum. exp2-domain softmax
// (Q projection pre-scaled by 0.125*log2(e)).
// R16: (1) GEMM BK=128 (8 iterations -> half the vmcnt(0)+barrier drains of
// R14; 64KB LDS/block, 2 blocks/CU -> 128KB <= 160KB, no cliff at this grid).
// (2) attn g-permutation table balancing per-CU tile sums (decode-only,
// bijective: each stride-4 slot quadruple sums to 30). attn body frozen
// (= R6/R10-R15, passed 7x); setprio kept (neutral).

typedef __attribute__((ext_vector_type(8))) short bf16x8;
typedef __attribute__((ext_vector_type(4))) float f32x4;
typedef __attribute__((ext_vector_type(16))) float f32x16;

__device__ __forceinline__ unsigned short f2bf(float f) {
  union { float f; unsigned u; } x; x.f = f;
  unsigned r = x.u + 0x7FFFu + ((x.u >> 16) & 1u);   // RNE
  return (unsigned short)(r >> 16);
}

__device__ __forceinline__ unsigned cvtpk_bf16(float lo, float hi) {
  unsigned r;
  asm("v_cvt_pk_bf16_f32 %0, %1, %2" : "=v"(r) : "v"(lo), "v"(hi));
  return r;
}

__device__ __forceinline__ f32x16 mfma32(bf16x8 a, bf16x8 b, f32x16 c) {
  return __builtin_amdgcn_mfma_f32_32x32x16_bf16(a, b, c, 0, 0, 0);
}

__device__ __forceinline__ void gld16(unsigned short* lds, const unsigned short* g) {
  __builtin_amdgcn_global_load_lds(
      (const __attribute__((address_space(1))) unsigned int*)g,
      (__attribute__((address_space(3))) unsigned int*)lds, 16, 0, 0);
}

// ---------------- weights-only fp32 -> bf16 cast (1 launch) ----------------
__global__ __launch_bounds__(256)
void cast_w(const float* __restrict__ wq, const float* __restrict__ wk,
            const float* __restrict__ wv, const float* __restrict__ wo,
            unsigned short* __restrict__ wqb, unsigned short* __restrict__ wkb,
            unsigned short* __restrict__ wvb, unsigned short* __restrict__ wob) {
  constexpr int W4 = 1024 * 1024 / 4;   // 262,144 float4 units per weight
  const int i = blockIdx.x * 256 + threadIdx.x;
  const int r = i / W4;
  const int off = i - r * W4;
  const float* src = (r == 0) ? wq : (r == 1) ? wk : (r == 2) ? wv : wo;
  unsigned short* dst = (r == 0) ? wqb : (r == 1) ? wkb : (r == 2) ? wvb : wob;
  const float4 f = ((const float4*)src)[off];
  ushort4 o;
  o.x = f2bf(f.x); o.y = f2bf(f.y); o.z = f2bf(f.z); o.w = f2bf(f.w);
  ((ushort4*)dst)[off] = o;
}

// ---------------- merged Q/K/V projection GEMM (one launch, 1536 blocks) ----------------
// which = blockIdx.x>>9 selects {0:Q(scale), 1:K, 2:V(transposed store)}.
// Per-512-group: flat XCD-chunked decode (R11). K-loop: BK=128 (R16), A staged
// fp32->reg->cvt_pk->ds_write (R12/R14 pattern). Epilogue branches runtime.
__global__ __launch_bounds__(256)
void gemm_qkv(const float* __restrict__ Aq, const float* __restrict__ Ak,
              const float* __restrict__ Av,
              const unsigned short* __restrict__ Wq, const unsigned short* __restrict__ Wk,
              const unsigned short* __restrict__ Wv,
              const float* __restrict__ bq, const float* __restrict__ bk,
              const float* __restrict__ bv,
              unsigned short* __restrict__ Qp, unsigned short* __restrict__ Kp,
              unsigned short* __restrict__ Vt,
              int M, int N, int K) {
  __shared__ unsigned short As[128 * 128];
  __shared__ unsigned short Bs[128 * 128];
  const int which = blockIdx.x >> 9;           // 0..2
  const int bid = blockIdx.x & 511;
  const float* Af = (which == 0) ? Aq : (which == 1) ? Ak : Av;
  const unsigned short* Bw = (which == 0) ? Wq : (which == 1) ? Wk : Wv;
  const float* bias = (which == 0) ? bq : (which == 1) ? bk : bv;

  const int tid = threadIdx.x;
  const int lane = tid & 63;
  const int w = tid >> 6;
  const int wm = (w >> 1) * 64;
  const int wn = (w & 1) * 64;
  const int xcd = bid & 7, jj = bid >> 3;
  const int m0 = (xcd * 8 + (jj >> 3)) * 128;
  const int n0 = (jj & 7) * 128;
  const int l15 = lane & 15, l4 = lane >> 4;

  f32x4 acc[4][4] = {};

  for (int k0 = 0; k0 < K; k0 += 128) {
    // issue fp32 A loads BEFORE the barrier (no LDS hazard; latency hidden)
    float4 av[8][2];
#pragma unroll
    for (int q = 0; q < 8; ++q) {
      const int c = q * 256 + tid;
      const int row = c >> 4, kc = (c & 15) * 8;
      const float4* ap = (const float4*)(Af + (size_t)(m0 + row) * K + k0 + kc);
      av[q][0] = ap[0];
      av[q][1] = ap[1];
    }
    __syncthreads();  // previous tile's LDS reads done
#pragma unroll
    for (int q = 0; q < 8; ++q) {
      const int c = q * 256 + tid;
      union { bf16x8 v; unsigned u[4]; } p;
      p.u[0] = cvtpk_bf16(av[q][0].x, av[q][0].y);
      p.u[1] = cvtpk_bf16(av[q][0].z, av[q][0].w);
      p.u[2] = cvtpk_bf16(av[q][1].x, av[q][1].y);
      p.u[3] = cvtpk_bf16(av[q][1].z, av[q][1].w);
      *(bf16x8*)&As[c * 8] = p.v;
    }
#pragma unroll
    for (int q = 0; q < 8; ++q) {
      const int c = q * 256 + tid;
      const int row = c >> 4, kc = (c & 15) * 8;
      gld16(&Bs[c * 8], &Bw[(size_t)(n0 + row) * K + k0 + kc]);
    }
    __syncthreads();  // publish A writes; drain B gld

#pragma unroll
    for (int kk = 0; kk < 4; ++kk) {
      bf16x8 af[4], bfr[4];
#pragma unroll
      for (int m = 0; m < 4; ++m)
        af[m] = *(const bf16x8*)&As[(wm + m * 16 + l15) * 128 + kk * 32 + l4 * 8];
#pragma unroll
      for (int n = 0; n < 4; ++n)
        bfr[n] = *(const bf16x8*)&Bs[(wn + n * 16 + l15) * 128 + kk * 32 + l4 * 8];
#pragma unroll
      for (int m = 0; m < 4; ++m)
#pragma unroll
        for (int n = 0; n < 4; ++n)
          acc[m][n] = __builtin_amdgcn_mfma_f32_16x16x32_bf16(af[m], bfr[n], acc[m][n], 0, 0, 0);
    }
  }

  const int crow = l4 * 4;
#pragma unroll
  for (int m = 0; m < 4; ++m) {
#pragma unroll
    for (int n = 0; n < 4; ++n) {
      const int col = n0 + wn + n * 16 + l15;
      const float bv_ = bias[col];
      if (which == 2) {
        // V: write transposed Vt[(b*16+h)*64+d][s], 4 consecutive s per 8B store
        constexpr int SS = 2048;
        const int rowb = m0 + wm + m * 16 + crow;      // multiple of 4
        const int b_ = rowb >> 11, s_ = rowb & (SS - 1);
        const int vrow = ((b_ << 4) + (col >> 6)) * 64 + (col & 63);
        uint2 pk;
        pk.x = cvtpk_bf16(acc[m][n][0] + bv_, acc[m][n][1] + bv_);
        pk.y = cvtpk_bf16(acc[m][n][2] + bv_, acc[m][n][3] + bv_);
        *(uint2*)&Vt[(size_t)vrow * SS + s_] = pk;
      } else {
        unsigned short* Cb = (which == 0) ? Qp : Kp;
        const float sc = (which == 0) ? 0.125f * 1.44269504f : 1.0f;
#pragma unroll
        for (int j = 0; j < 4; ++j) {
          const int row = m0 + wm + m * 16 + crow + j;
          Cb[(size_t)row * N + col] = f2bf((acc[m][n][j] + bv_) * sc);
        }
      }
    }
  }
}

// ---------------- output projection GEMM (bf16 A via gld16, fp32 out) ----------------
__global__ __launch_bounds__(256)
void gemm_out(const unsigned short* __restrict__ Ab,
              const unsigned short* __restrict__ Bw,
              const float* __restrict__ bias,
              float* __restrict__ Cf,
              int M, int N, int K) {
  __shared__ unsigned short As[128 * 128];
  __shared__ unsigned short Bs[128 * 128];
  const int tid = threadIdx.x;
  const int lane = tid & 63;
  const int w = tid >> 6;
  const int wm = (w >> 1) * 64;
  const int wn = (w & 1) * 64;
  const int bid = blockIdx.x;
  const int xcd = bid & 7, jj = bid >> 3;
  const int m0 = (xcd * 8 + (jj >> 3)) * 128;
  const int n0 = (jj & 7) * 128;
  const int l15 = lane & 15, l4 = lane >> 4;

  f32x4 acc[4][4] = {};

  for (int k0 = 0; k0 < K; k0 += 128) {
    __syncthreads();
#pragma unroll
    for (int q = 0; q < 8; ++q) {
      const int c = q * 256 + tid;
      const int row = c >> 4, kc = (c & 15) * 8;
      gld16(&As[c * 8], &Ab[(size_t)(m0 + row) * K + k0 + kc]);
      gld16(&Bs[c * 8], &Bw[(size_t)(n0 + row) * K + k0 + kc]);
    }
    __syncthreads();

#pragma unroll
    for (int kk = 0; kk < 4; ++kk) {
      bf16x8 af[4], bfr[4];
#pragma unroll
      for (int m = 0; m < 4; ++m)
        af[m] = *(const bf16x8*)&As[(wm + m * 16 + l15) * 128 + kk * 32 + l4 * 8];
#pragma unroll
      for (int n = 0; n < 4; ++n)
        bfr[n] = *(const bf16x8*)&Bs[(wn + n * 16 + l15) * 128 + kk * 32 + l4 * 8];
#pragma unroll
      for (int m = 0; m < 4; ++m)
#pragma unroll
        for (int n = 0; n < 4; ++n)
          acc[m][n] = __builtin_amdgcn_mfma_f32_16x16x32_bf16(af[m], bfr[n], acc[m][n], 0, 0, 0);
    }
  }

  const int crow = l4 * 4;
#pragma unroll
  for (int m = 0; m < 4; ++m) {
#pragma unroll
    for (int n = 0; n < 4; ++n) {
      const int col = n0 + wn + n * 16 + l15;
      const float bv_ = bias[col];
#pragma unroll
      for (int j = 0; j < 4; ++j) {
        const int row = m0 + wm + m * 16 + crow + j;
        Cf[(size_t)row * N + col] = acc[m][n][j] + bv_;
      }
    }
  }
}

// ---------------- flash attention, causal, cooperative 4-wave blocks ----------------
// FROZEN body (= R6/R10-R15, passed seven times). ONLY change: g decoded via
// a balance table so every CU's 4 resident blocks sum to equal work
// (slots {s,s+4,s+8,s+12} all sum to 30). Bijective on g in 0..15.
__global__ __launch_bounds__(256)
void attn_fwd32b(const unsigned short* __restrict__ Qp,   // [B*S,1024] bf16 (scaled)
                 const unsigned short* __restrict__ Kp,   // [B*S,1024] bf16
                 const unsigned short* __restrict__ Vt,   // [(b*16+h)*64+d, S] bf16
                 unsigned short* __restrict__ Xo) {       // [B*S,1024] bf16
  constexpr int S = 2048, Dm = 1024;
  const int bh = blockIdx.x & 63;
  constexpr int GTBL[16] = {15, 14, 13, 12, 8, 9, 10, 11, 7, 6, 5, 4, 0, 1, 2, 3};
  const int g = GTBL[blockIdx.x >> 6];          // balanced per-CU work
  const int b = bh >> 4, h = bh & 15;
  const int w = threadIdx.x >> 6;
  const int lane = threadIdx.x & 63;
  const int l31 = lane & 31, hi = lane >> 5;
  const int qb = 4 * g + w;
  const int qrow = qb * 32 + l31;
  const int ntw = qb + 1;          // this wave's KV tiles; tile ntw-1 masked
  const int NT = 4 * g + 4;        // uniform block trip count (even)

  // Q B-frags: col=q=l31, k(d)=c*16+hi*8
  const unsigned short* qptr = Qp + (size_t)(b * S + qrow) * Dm + h * 64 + hi * 8;
  bf16x8 qf[4];
#pragma unroll
  for (int c = 0; c < 4; ++c) qf[c] = *(const bf16x8*)(qptr + c * 16);

  const unsigned short* kbase = Kp + (size_t)(b * S) * Dm + h * 64 + hi * 8;
  const unsigned short* vr0 = Vt + (size_t)(bh * 64 + l31) * S + hi * 8;
  const unsigned short* vr1 = vr0 + (size_t)32 * S;

  f32x16 ot0 = {}, ot1 = {};   // O^T: rows d (0-31 / 32-63), col q=l31
  float m = -1e30f, l = 0.f;

  auto loadK = [&](bf16x8 (&kr)[4], int t) {
    const unsigned short* krow = kbase + (size_t)(t * 32 + l31) * Dm;
#pragma unroll
    for (int c = 0; c < 4; ++c) kr[c] = *(const bf16x8*)(krow + c * 16);
  };

  auto body = [&](bf16x8 (&kr)[4], int t) {
    const int kv0 = t * 32;
    // V loads issued early; consumed after softmax
    const bf16x8 vf0a = *(const bf16x8*)(vr0 + kv0);
    const bf16x8 vf0b = *(const bf16x8*)(vr0 + kv0 + 16);
    const bf16x8 vf1a = *(const bf16x8*)(vr1 + kv0);
    const bf16x8 vf1b = *(const bf16x8*)(vr1 + kv0 + 16);
    // S^T = K · Q  (rows kv, col q)
    f32x16 ts = {};
    __builtin_amdgcn_s_setprio(1);
#pragma unroll
    for (int c = 0; c < 4; ++c) ts = mfma32(kr[c], qf[c], ts);
    __builtin_amdgcn_s_setprio(0);
    if (t == ntw - 1) {   // diagonal tile
#pragma unroll
      for (int r = 0; r < 16; ++r) {
        const int kvp = kv0 + (r & 3) + 8 * (r >> 2) + 4 * hi;
        if (kvp > qrow) ts[r] = -1e9f;
      }
    }
    // row max: lane-local + 1 cross-half shfl
    float pmax = ts[0];
#pragma unroll
    for (int r = 1; r < 16; ++r) pmax = fmaxf(pmax, ts[r]);
    pmax = fmaxf(pmax, __shfl_xor(pmax, 32));
    // deferred rescale (T13; log2 units)
    if (__any(pmax > m + 11.5f)) {
      const float mn = (pmax > m + 11.5f) ? pmax : m;
      const float fct = __builtin_amdgcn_exp2f(m - mn);
      m = mn; l *= fct;
#pragma unroll
      for (int r = 0; r < 16; ++r) { ot0[r] *= fct; ot1[r] *= fct; }
    }
    // p = 2^(s-m), row-sum
    float p[16], ls = 0.f;
#pragma unroll
    for (int r = 0; r < 16; ++r) {
      p[r] = __builtin_amdgcn_exp2f(ts[r] - m);
      ls += p[r];
    }
    ls += __shfl_xor(ls, 32);
    l += ls;
    // pack bf16 pairs + cross-half exchange -> P^T B-frags (k=kv)
    unsigned ua[8];
#pragma unroll
    for (int i = 0; i < 8; ++i) ua[i] = cvtpk_bf16(p[2 * i], p[2 * i + 1]);
    union FR { bf16x8 v; unsigned u[4]; } fr0, fr1;
    {
      unsigned sa = hi ? ua[0] : ua[2], sb = hi ? ua[1] : ua[3];
      unsigned xa = __shfl_xor(sa, 32), xb = __shfl_xor(sb, 32);
      fr0.u[0] = hi ? xa : ua[0]; fr0.u[1] = hi ? xb : ua[1];
      fr0.u[2] = hi ? ua[2] : xa; fr0.u[3] = hi ? ua[3] : xb;
      unsigned sc = hi ? ua[4] : ua[6], sd = hi ? ua[5] : ua[7];
      unsigned xc = __shfl_xor(sc, 32), xd = __shfl_xor(sd, 32);
      fr1.u[0] = hi ? xc : ua[4]; fr1.u[1] = hi ? xd : ua[5];
      fr1.u[2] = hi ? ua[6] : xc; fr1.u[3] = hi ? ua[7] : xd;
    }
    // O^T += V^T · P^T
    __builtin_amdgcn_s_setprio(1);
    ot0 = mfma32(vf0a, fr0.v, ot0);
    ot0 = mfma32(vf0b, fr1.v, ot0);
    ot1 = mfma32(vf1a, fr0.v, ot1);
    ot1 = mfma32(vf1b, fr1.v, ot1);
    __builtin_amdgcn_s_setprio(0);
  };

  // ping-pong K prefetch; identical loads across the 4 waves (L1-shared).
  bf16x8 kA[4], kB[4];
  loadK(kA, 0);
  for (int t = 0; t < NT; t += 2) {
    loadK(kB, t + 1);
    if (t < ntw) body(kA, t);
    __builtin_amdgcn_s_barrier();
    const int t2 = (t + 2 < NT) ? (t + 2) : (NT - 1);  // clamped (redundant on last)
    loadK(kA, t2);
    if (t + 1 < ntw) body(kB, t + 1);
    __builtin_amdgcn_s_barrier();
  }

  // epilogue: normalize (lane-local l), pack pairs, 8B stores
  const float inv = 1.f / l;
  unsigned short* orow = Xo + (size_t)(b * S + qrow) * Dm + h * 64;
#pragma unroll
  for (int rq = 0; rq < 4; ++rq) {
    uint2 pr;
    pr.x = cvtpk_bf16(ot0[4 * rq + 0] * inv, ot0[4 * rq + 1] * inv);
    pr.y = cvtpk_bf16(ot0[4 * rq + 2] * inv, ot0[4 * rq + 3] * inv);
    *(uint2*)(orow + 8 * rq + 4 * hi) = pr;
    uint2 pr1;
    pr1.x = cvtpk_bf16(ot1[4 * rq + 0] * inv, ot1[4 * rq + 1] * inv);
    pr1.y = cvtpk_bf16(ot1[4 * rq + 2] * inv, ot1[4 * rq + 3] * inv);
    *(uint2*)(orow + 32 + 8 * rq + 4 * hi) = pr1;
  }
}

// ---------------- launch ----------------
extern "C" void kernel_launch(void* const* d_in, const int* in_sizes, int n_in,
                              void* d_out, int out_size, void* d_ws, size_t ws_size,
                              hipStream_t stream) {
  const float* query = (const float*)d_in[0];
  const float* key   = (const float*)d_in[1];
  const float* value = (const float*)d_in[2];
  const float* Wq = (const float*)d_in[4];
  const float* bq = (const float*)d_in[5];
  const float* Wk = (const float*)d_in[6];
  const float* bk = (const float*)d_in[7];
  const float* Wv = (const float*)d_in[8];
  const float* bv = (const float*)d_in[9];
  const float* Wo = (const float*)d_in[10];
  const float* bo = (const float*)d_in[11];

  constexpr int B = 4, S = 2048, D = 1024;
  constexpr int M = B * S;
  const size_t MB = 1024u * 1024u;
  uint8_t* ws = (uint8_t*)d_ws;

  unsigned short* Wqb = (unsigned short*)(ws + 48 * MB);
  unsigned short* Wkb = (unsigned short*)(ws + 50 * MB);
  unsigned short* Wvb = (unsigned short*)(ws + 52 * MB);
  unsigned short* Wob = (unsigned short*)(ws + 54 * MB);
  unsigned short* Qp  = (unsigned short*)(ws + 56 * MB);
  unsigned short* Kp  = (unsigned short*)(ws + 72 * MB);
  unsigned short* Vt  = (unsigned short*)(ws + 32 * MB);
  unsigned short* Xat = (unsigned short*)(ws + 16 * MB);

  // weights-only cast: 4*W4 float4 units
  constexpr int W4 = D * D / 4;
  cast_w<<<4 * W4 / 256, 256, 0, stream>>>(Wq, Wk, Wv, Wo, Wqb, Wkb, Wvb, Wob);

  // merged Q/K/V projections: one 1536-block launch, BK=128
  gemm_qkv<<<1536, 256, 0, stream>>>(query, key, value, Wqb, Wkb, Wvb,
                                     bq, bk, bv, Qp, Kp, Vt, M, D, D);

  attn_fwd32b<<<1024, 256, 0, stream>>>(Qp, Kp, Vt, Xat);

  // output projection: A already bf16, fp32 out, BK=128
  gemm_out<<<512, 256, 0, stream>>>(Xat, Wob, bo, (float*)d_out, M, D, D);
}

// Round 18
// 261.114 us; speedup vs baseline: 1.3938x; 1.3938x over previous
//
#include <hip/hip_runtime.h>
#include <cstdint>
#include <cstddef>

// MHA: out = softmax_causal((XqWq^T+bq)(XkWk^T+bk)^T / 8) (XvWv^T+bv) Wo^T + bo
// B=4 S=2048 D=1024 H=16 dk=64. bf16 MFMA, fp32 accum. exp2-domain softmax
// (Q projection pre-scaled by 0.125*log2(e)).
// R17: REVERT GEMMs to R15's verified BK=64 (R16's BK=128 regressed 2x:
// 4.4e7 bank conflicts from 256B row stride + 64KB-LDS occupancy floor).
// attn keeps R16's GTBL per-CU balance permutation (passed; A/B vs R15's
// 138.5us tells us its isolated effect). setprio kept (neutral).
// Verified stack: XCD-decode(R11) CASTA(R12) TRANSV(R13) BK=64(R14) merge(R15).

typedef __attribute__((ext_vector_type(8))) short bf16x8;
typedef __attribute__((ext_vector_type(4))) float f32x4;
typedef __attribute__((ext_vector_type(16))) float f32x16;

__device__ __forceinline__ unsigned short f2bf(float f) {
  union { float f; unsigned u; } x; x.f = f;
  unsigned r = x.u + 0x7FFFu + ((x.u >> 16) & 1u);   // RNE
  return (unsigned short)(r >> 16);
}

__device__ __forceinline__ unsigned cvtpk_bf16(float lo, float hi) {
  unsigned r;
  asm("v_cvt_pk_bf16_f32 %0, %1, %2" : "=v"(r) : "v"(lo), "v"(hi));
  return r;
}

__device__ __forceinline__ f32x16 mfma32(bf16x8 a, bf16x8 b, f32x16 c) {
  return __builtin_amdgcn_mfma_f32_32x32x16_bf16(a, b, c, 0, 0, 0);
}

__device__ __forceinline__ void gld16(unsigned short* lds, const unsigned short* g) {
  __builtin_amdgcn_global_load_lds(
      (const __attribute__((address_space(1))) unsigned int*)g,
      (__attribute__((address_space(3))) unsigned int*)lds, 16, 0, 0);
}

// ---------------- weights-only fp32 -> bf16 cast (1 launch) ----------------
__global__ __launch_bounds__(256)
void cast_w(const float* __restrict__ wq, const float* __restrict__ wk,
            const float* __restrict__ wv, const float* __restrict__ wo,
            unsigned short* __restrict__ wqb, unsigned short* __restrict__ wkb,
            unsigned short* __restrict__ wvb, unsigned short* __restrict__ wob) {
  constexpr int W4 = 1024 * 1024 / 4;   // 262,144 float4 units per weight
  const int i = blockIdx.x * 256 + threadIdx.x;
  const int r = i / W4;
  const int off = i - r * W4;
  const float* src = (r == 0) ? wq : (r == 1) ? wk : (r == 2) ? wv : wo;
  unsigned short* dst = (r == 0) ? wqb : (r == 1) ? wkb : (r == 2) ? wvb : wob;
  const float4 f = ((const float4*)src)[off];
  ushort4 o;
  o.x = f2bf(f.x); o.y = f2bf(f.y); o.z = f2bf(f.z); o.w = f2bf(f.w);
  ((ushort4*)dst)[off] = o;
}

// ---------------- merged Q/K/V projection GEMM (one launch, 1536 blocks) ----------------
// which = blockIdx.x>>9 selects {0:Q(scale), 1:K, 2:V(transposed store)}.
// Per-512-group: flat XCD-chunked decode (R11). K-loop: BK=64, A staged
// fp32->reg->cvt_pk->ds_write (R12/R14, verified). Epilogue branches runtime.
__global__ __launch_bounds__(256)
void gemm_qkv(const float* __restrict__ Aq, const float* __restrict__ Ak,
              const float* __restrict__ Av,
              const unsigned short* __restrict__ Wq, const unsigned short* __restrict__ Wk,
              const unsigned short* __restrict__ Wv,
              const float* __restrict__ bq, const float* __restrict__ bk,
              const float* __restrict__ bv,
              unsigned short* __restrict__ Qp, unsigned short* __restrict__ Kp,
              unsigned short* __restrict__ Vt,
              int M, int N, int K) {
  __shared__ unsigned short As[128 * 64];
  __shared__ unsigned short Bs[128 * 64];
  const int which = blockIdx.x >> 9;           // 0..2
  const int bid = blockIdx.x & 511;
  const float* Af = (which == 0) ? Aq : (which == 1) ? Ak : Av;
  const unsigned short* Bw = (which == 0) ? Wq : (which == 1) ? Wk : Wv;
  const float* bias = (which == 0) ? bq : (which == 1) ? bk : bv;

  const int tid = threadIdx.x;
  const int lane = tid & 63;
  const int w = tid >> 6;
  const int wm = (w >> 1) * 64;
  const int wn = (w & 1) * 64;
  const int xcd = bid & 7, jj = bid >> 3;
  const int m0 = (xcd * 8 + (jj >> 3)) * 128;
  const int n0 = (jj & 7) * 128;
  const int l15 = lane & 15, l4 = lane >> 4;

  f32x4 acc[4][4] = {};

  for (int k0 = 0; k0 < K; k0 += 64) {
    // issue fp32 A loads BEFORE the barrier (no LDS hazard; latency hidden)
    float4 av[4][2];
#pragma unroll
    for (int q = 0; q < 4; ++q) {
      const int c = q * 256 + tid;
      const int row = c >> 3, kc = (c & 7) * 8;
      const float4* ap = (const float4*)(Af + (size_t)(m0 + row) * K + k0 + kc);
      av[q][0] = ap[0];
      av[q][1] = ap[1];
    }
    __syncthreads();  // previous tile's LDS reads done
#pragma unroll
    for (int q = 0; q < 4; ++q) {
      const int c = q * 256 + tid;
      union { bf16x8 v; unsigned u[4]; } p;
      p.u[0] = cvtpk_bf16(av[q][0].x, av[q][0].y);
      p.u[1] = cvtpk_bf16(av[q][0].z, av[q][0].w);
      p.u[2] = cvtpk_bf16(av[q][1].x, av[q][1].y);
      p.u[3] = cvtpk_bf16(av[q][1].z, av[q][1].w);
      *(bf16x8*)&As[c * 8] = p.v;
    }
#pragma unroll
    for (int q = 0; q < 4; ++q) {
      const int c = q * 256 + tid;
      const int row = c >> 3, kc = (c & 7) * 8;
      gld16(&Bs[c * 8], &Bw[(size_t)(n0 + row) * K + k0 + kc]);
    }
    __syncthreads();  // publish A writes; drain B gld

#pragma unroll
    for (int kk = 0; kk < 2; ++kk) {
      bf16x8 af[4], bfr[4];
#pragma unroll
      for (int m = 0; m < 4; ++m)
        af[m] = *(const bf16x8*)&As[(wm + m * 16 + l15) * 64 + kk * 32 + l4 * 8];
#pragma unroll
      for (int n = 0; n < 4; ++n)
        bfr[n] = *(const bf16x8*)&Bs[(wn + n * 16 + l15) * 64 + kk * 32 + l4 * 8];
#pragma unroll
      for (int m = 0; m < 4; ++m)
#pragma unroll
        for (int n = 0; n < 4; ++n)
          acc[m][n] = __builtin_amdgcn_mfma_f32_16x16x32_bf16(af[m], bfr[n], acc[m][n], 0, 0, 0);
    }
  }

  const int crow = l4 * 4;
#pragma unroll
  for (int m = 0; m < 4; ++m) {
#pragma unroll
    for (int n = 0; n < 4; ++n) {
      const int col = n0 + wn + n * 16 + l15;
      const float bv_ = bias[col];
      if (which == 2) {
        // V: write transposed Vt[(b*16+h)*64+d][s], 4 consecutive s per 8B store
        constexpr int SS = 2048;
        const int rowb = m0 + wm + m * 16 + crow;      // multiple of 4
        const int b_ = rowb >> 11, s_ = rowb & (SS - 1);
        const int vrow = ((b_ << 4) + (col >> 6)) * 64 + (col & 63);
        uint2 pk;
        pk.x = cvtpk_bf16(acc[m][n][0] + bv_, acc[m][n][1] + bv_);
        pk.y = cvtpk_bf16(acc[m][n][2] + bv_, acc[m][n][3] + bv_);
        *(uint2*)&Vt[(size_t)vrow * SS + s_] = pk;
      } else {
        unsigned short* Cb = (which == 0) ? Qp : Kp;
        const float sc = (which == 0) ? 0.125f * 1.44269504f : 1.0f;
#pragma unroll
        for (int j = 0; j < 4; ++j) {
          const int row = m0 + wm + m * 16 + crow + j;
          Cb[(size_t)row * N + col] = f2bf((acc[m][n][j] + bv_) * sc);
        }
      }
    }
  }
}

// ---------------- output projection GEMM (bf16 A via gld16, fp32 out) ----------------
__global__ __launch_bounds__(256)
void gemm_out(const unsigned short* __restrict__ Ab,
              const unsigned short* __restrict__ Bw,
              const float* __restrict__ bias,
              float* __restrict__ Cf,
              int M, int N, int K) {
  __shared__ unsigned short As[128 * 64];
  __shared__ unsigned short Bs[128 * 64];
  const int tid = threadIdx.x;
  const int lane = tid & 63;
  const int w = tid >> 6;
  const int wm = (w >> 1) * 64;
  const int wn = (w & 1) * 64;
  const int bid = blockIdx.x;
  const int xcd = bid & 7, jj = bid >> 3;
  const int m0 = (xcd * 8 + (jj >> 3)) * 128;
  const int n0 = (jj & 7) * 128;
  const int l15 = lane & 15, l4 = lane >> 4;

  f32x4 acc[4][4] = {};

  for (int k0 = 0; k0 < K; k0 += 64) {
    __syncthreads();
#pragma unroll
    for (int q = 0; q < 4; ++q) {
      const int c = q * 256 + tid;
      const int row = c >> 3, kc = (c & 7) * 8;
      gld16(&As[c * 8], &Ab[(size_t)(m0 + row) * K + k0 + kc]);
      gld16(&Bs[c * 8], &Bw[(size_t)(n0 + row) * K + k0 + kc]);
    }
    __syncthreads();

#pragma unroll
    for (int kk = 0; kk < 2; ++kk) {
      bf16x8 af[4], bfr[4];
#pragma unroll
      for (int m = 0; m < 4; ++m)
        af[m] = *(const bf16x8*)&As[(wm + m * 16 + l15) * 64 + kk * 32 + l4 * 8];
#pragma unroll
      for (int n = 0; n < 4; ++n)
        bfr[n] = *(const bf16x8*)&Bs[(wn + n * 16 + l15) * 64 + kk * 32 + l4 * 8];
#pragma unroll
      for (int m = 0; m < 4; ++m)
#pragma unroll
        for (int n = 0; n < 4; ++n)
          acc[m][n] = __builtin_amdgcn_mfma_f32_16x16x32_bf16(af[m], bfr[n], acc[m][n], 0, 0, 0);
    }
  }

  const int crow = l4 * 4;
#pragma unroll
  for (int m = 0; m < 4; ++m) {
#pragma unroll
    for (int n = 0; n < 4; ++n) {
      const int col = n0 + wn + n * 16 + l15;
      const float bv_ = bias[col];
#pragma unroll
      for (int j = 0; j < 4; ++j) {
        const int row = m0 + wm + m * 16 + crow + j;
        Cf[(size_t)row * N + col] = acc[m][n][j] + bv_;
      }
    }
  }
}

// ---------------- flash attention, causal, cooperative 4-wave blocks ----------------
// FROZEN body (= R6/R10-R15, passed eight times). g decoded via the balance
// table (R16, passed): slots {s,s+4,s+8,s+12} sum to 30 -> equal per-CU work.
__global__ __launch_bounds__(256)
void attn_fwd32b(const unsigned short* __restrict__ Qp,   // [B*S,1024] bf16 (scaled)
                 const unsigned short* __restrict__ Kp,   // [B*S,1024] bf16
                 const unsigned short* __restrict__ Vt,   // [(b*16+h)*64+d, S] bf16
                 unsigned short* __restrict__ Xo) {       // [B*S,1024] bf16
  constexpr int S = 2048, Dm = 1024;
  const int bh = blockIdx.x & 63;
  constexpr int GTBL[16] = {15, 14, 13, 12, 8, 9, 10, 11, 7, 6, 5, 4, 0, 1, 2, 3};
  const int g = GTBL[blockIdx.x >> 6];          // balanced per-CU work
  const int b = bh >> 4, h = bh & 15;
  const int w = threadIdx.x >> 6;
  const int lane = threadIdx.x & 63;
  const int l31 = lane & 31, hi = lane >> 5;
  const int qb = 4 * g + w;
  const int qrow = qb * 32 + l31;
  const int ntw = qb + 1;          // this wave's KV tiles; tile ntw-1 masked
  const int NT = 4 * g + 4;        // uniform block trip count (even)

  // Q B-frags: col=q=l31, k(d)=c*16+hi*8
  const unsigned short* qptr = Qp + (size_t)(b * S + qrow) * Dm + h * 64 + hi * 8;
  bf16x8 qf[4];
#pragma unroll
  for (int c = 0; c < 4; ++c) qf[c] = *(const bf16x8*)(qptr + c * 16);

  const unsigned short* kbase = Kp + (size_t)(b * S) * Dm + h * 64 + hi * 8;
  const unsigned short* vr0 = Vt + (size_t)(bh * 64 + l31) * S + hi * 8;
  const unsigned short* vr1 = vr0 + (size_t)32 * S;

  f32x16 ot0 = {}, ot1 = {};   // O^T: rows d (0-31 / 32-63), col q=l31
  float m = -1e30f, l = 0.f;

  auto loadK = [&](bf16x8 (&kr)[4], int t) {
    const unsigned short* krow = kbase + (size_t)(t * 32 + l31) * Dm;
#pragma unroll
    for (int c = 0; c < 4; ++c) kr[c] = *(const bf16x8*)(krow + c * 16);
  };

  auto body = [&](bf16x8 (&kr)[4], int t) {
    const int kv0 = t * 32;
    // V loads issued early; consumed after softmax
    const bf16x8 vf0a = *(const bf16x8*)(vr0 + kv0);
    const bf16x8 vf0b = *(const bf16x8*)(vr0 + kv0 + 16);
    const bf16x8 vf1a = *(const bf16x8*)(vr1 + kv0);
    const bf16x8 vf1b = *(const bf16x8*)(vr1 + kv0 + 16);
    // S^T = K · Q  (rows kv, col q)
    f32x16 ts = {};
    __builtin_amdgcn_s_setprio(1);
#pragma unroll
    for (int c = 0; c < 4; ++c) ts = mfma32(kr[c], qf[c], ts);
    __builtin_amdgcn_s_setprio(0);
    if (t == ntw - 1) {   // diagonal tile
#pragma unroll
      for (int r = 0; r < 16; ++r) {
        const int kvp = kv0 + (r & 3) + 8 * (r >> 2) + 4 * hi;
        if (kvp > qrow) ts[r] = -1e9f;
      }
    }
    // row max: lane-local + 1 cross-half shfl
    float pmax = ts[0];
#pragma unroll
    for (int r = 1; r < 16; ++r) pmax = fmaxf(pmax, ts[r]);
    pmax = fmaxf(pmax, __shfl_xor(pmax, 32));
    // deferred rescale (T13; log2 units)
    if (__any(pmax > m + 11.5f)) {
      const float mn = (pmax > m + 11.5f) ? pmax : m;
      const float fct = __builtin_amdgcn_exp2f(m - mn);
      m = mn; l *= fct;
#pragma unroll
      for (int r = 0; r < 16; ++r) { ot0[r] *= fct; ot1[r] *= fct; }
    }
    // p = 2^(s-m), row-sum
    float p[16], ls = 0.f;
#pragma unroll
    for (int r = 0; r < 16; ++r) {
      p[r] = __builtin_amdgcn_exp2f(ts[r] - m);
      ls += p[r];
    }
    ls += __shfl_xor(ls, 32);
    l += ls;
    // pack bf16 pairs + cross-half exchange -> P^T B-frags (k=kv)
    unsigned ua[8];
#pragma unroll
    for (int i = 0; i < 8; ++i) ua[i] = cvtpk_bf16(p[2 * i], p[2 * i + 1]);
    union FR { bf16x8 v; unsigned u[4]; } fr0, fr1;
    {
      unsigned sa = hi ? ua[0] : ua[2], sb = hi ? ua[1] : ua[3];
      unsigned xa = __shfl_xor(sa, 32), xb = __shfl_xor(sb, 32);
      fr0.u[0] = hi ? xa : ua[0]; fr0.u[1] = hi ? xb : ua[1];
      fr0.u[2] = hi ? ua[2] : xa; fr0.u[3] = hi ? ua[3] : xb;
      unsigned sc = hi ? ua[4] : ua[6], sd = hi ? ua[5] : ua[7];
      unsigned xc = __shfl_xor(sc, 32), xd = __shfl_xor(sd, 32);
      fr1.u[0] = hi ? xc : ua[4]; fr1.u[1] = hi ? xd : ua[5];
      fr1.u[2] = hi ? ua[6] : xc; fr1.u[3] = hi ? ua[7] : xd;
    }
    // O^T += V^T · P^T
    __builtin_amdgcn_s_setprio(1);
    ot0 = mfma32(vf0a, fr0.v, ot0);
    ot0 = mfma32(vf0b, fr1.v, ot0);
    ot1 = mfma32(vf1a, fr0.v, ot1);
    ot1 = mfma32(vf1b, fr1.v, ot1);
    __builtin_amdgcn_s_setprio(0);
  };

  // ping-pong K prefetch; identical loads across the 4 waves (L1-shared).
  bf16x8 kA[4], kB[4];
  loadK(kA, 0);
  for (int t = 0; t < NT; t += 2) {
    loadK(kB, t + 1);
    if (t < ntw) body(kA, t);
    __builtin_amdgcn_s_barrier();
    const int t2 = (t + 2 < NT) ? (t + 2) : (NT - 1);  // clamped (redundant on last)
    loadK(kA, t2);
    if (t + 1 < ntw) body(kB, t + 1);
    __builtin_amdgcn_s_barrier();
  }

  // epilogue: normalize (lane-local l), pack pairs, 8B stores
  const float inv = 1.f / l;
  unsigned short* orow = Xo + (size_t)(b * S + qrow) * Dm + h * 64;
#pragma unroll
  for (int rq = 0; rq < 4; ++rq) {
    uint2 pr;
    pr.x = cvtpk_bf16(ot0[4 * rq + 0] * inv, ot0[4 * rq + 1] * inv);
    pr.y = cvtpk_bf16(ot0[4 * rq + 2] * inv, ot0[4 * rq + 3] * inv);
    *(uint2*)(orow + 8 * rq + 4 * hi) = pr;
    uint2 pr1;
    pr1.x = cvtpk_bf16(ot1[4 * rq + 0] * inv, ot1[4 * rq + 1] * inv);
    pr1.y = cvtpk_bf16(ot1[4 * rq + 2] * inv, ot1[4 * rq + 3] * inv);
    *(uint2*)(orow + 32 + 8 * rq + 4 * hi) = pr1;
  }
}

// ---------------- launch ----------------
extern "C" void kernel_launch(void* const* d_in, const int* in_sizes, int n_in,
                              void* d_out, int out_size, void* d_ws, size_t ws_size,
                              hipStream_t stream) {
  const float* query = (const float*)d_in[0];
  const float* key   = (const float*)d_in[1];
  const float* value = (const float*)d_in[2];
  const float* Wq = (const float*)d_in[4];
  const float* bq = (const float*)d_in[5];
  const float* Wk = (const float*)d_in[6];
  const float* bk = (const float*)d_in[7];
  const float* Wv = (const float*)d_in[8];
  const float* bv = (const float*)d_in[9];
  const float* Wo = (const float*)d_in[10];
  const float* bo = (const float*)d_in[11];

  constexpr int B = 4, S = 2048, D = 1024;
  constexpr int M = B * S;
  const size_t MB = 1024u * 1024u;
  uint8_t* ws = (uint8_t*)d_ws;

  unsigned short* Wqb = (unsigned short*)(ws + 48 * MB);
  unsigned short* Wkb = (unsigned short*)(ws + 50 * MB);
  unsigned short* Wvb = (unsigned short*)(ws + 52 * MB);
  unsigned short* Wob = (unsigned short*)(ws + 54 * MB);
  unsigned short* Qp  = (unsigned short*)(ws + 56 * MB);
  unsigned short* Kp  = (unsigned short*)(ws + 72 * MB);
  unsigned short* Vt  = (unsigned short*)(ws + 32 * MB);
  unsigned short* Xat = (unsigned short*)(ws + 16 * MB);

  // weights-only cast: 4*W4 float4 units
  constexpr int W4 = D * D / 4;
  cast_w<<<4 * W4 / 256, 256, 0, stream>>>(Wq, Wk, Wv, Wo, Wqb, Wkb, Wvb, Wob);

  // merged Q/K/V projections: one 1536-block launch, BK=64
  gemm_qkv<<<1536, 256, 0, stream>>>(query, key, value, Wqb, Wkb, Wvb,
                                     bq, bk, bv, Qp, Kp, Vt, M, D, D);

  attn_fwd32b<<<1024, 256, 0, stream>>>(Qp, Kp, Vt, Xat);

  // output projection: A already bf16, fp32 out, BK=64
  gemm_out<<<512, 256, 0, stream>>>(Xat, Wob, bo, (float*)d_out, M, D, D);
}

// Round 19
// 245.431 us; speedup vs baseline: 1.4829x; 1.0639x over previous
//
#include <hip/hip_runtime.h>
#include <cstdint>
#include <cstddef>

// MHA: out = softmax_causal((XqWq^T+bq)(XkWk^T+bk)^T / 8) (XvWv^T+bv) Wo^T + bo
// B=4 S=2048 D=1024 H=16 dk=64. bf16 MFMA, fp32 accum. exp2-domain softmax
// (Q projection pre-scaled by 0.125*log2(e)).
// R18: (1) attn GTBL REVERTED (R17 A/B: 146 vs 138 -> table hurt; plain
// descending g restored, = R15 exact). (2) GEMM LDS rows padded to 72 shorts
// (144B): BK=64's 128B stride was a 16-way ds_read_b128 bank conflict;
// pad -> 2-way (free). B staged via reg+ds_write (CASTA pattern, proven since
// R12) because gld16 needs contiguous dest. Write conflicts unchanged (8-way).
// Verified stack: XCD-decode(R11) CASTA(R12) TRANSV(R13) BK=64(R14) merge(R15).

typedef __attribute__((ext_vector_type(8))) short bf16x8;
typedef __attribute__((ext_vector_type(4))) float f32x4;
typedef __attribute__((ext_vector_type(16))) float f32x16;

__device__ __forceinline__ unsigned short f2bf(float f) {
  union { float f; unsigned u; } x; x.f = f;
  unsigned r = x.u + 0x7FFFu + ((x.u >> 16) & 1u);   // RNE
  return (unsigned short)(r >> 16);
}

__device__ __forceinline__ unsigned cvtpk_bf16(float lo, float hi) {
  unsigned r;
  asm("v_cvt_pk_bf16_f32 %0, %1, %2" : "=v"(r) : "v"(lo), "v"(hi));
  return r;
}

__device__ __forceinline__ f32x16 mfma32(bf16x8 a, bf16x8 b, f32x16 c) {
  return __builtin_amdgcn_mfma_f32_32x32x16_bf16(a, b, c, 0, 0, 0);
}

// ---------------- weights-only fp32 -> bf16 cast (1 launch) ----------------
__global__ __launch_bounds__(256)
void cast_w(const float* __restrict__ wq, const float* __restrict__ wk,
            const float* __restrict__ wv, const float* __restrict__ wo,
            unsigned short* __restrict__ wqb, unsigned short* __restrict__ wkb,
            unsigned short* __restrict__ wvb, unsigned short* __restrict__ wob) {
  constexpr int W4 = 1024 * 1024 / 4;   // 262,144 float4 units per weight
  const int i = blockIdx.x * 256 + threadIdx.x;
  const int r = i / W4;
  const int off = i - r * W4;
  const float* src = (r == 0) ? wq : (r == 1) ? wk : (r == 2) ? wv : wo;
  unsigned short* dst = (r == 0) ? wqb : (r == 1) ? wkb : (r == 2) ? wvb : wob;
  const float4 f = ((const float4*)src)[off];
  ushort4 o;
  o.x = f2bf(f.x); o.y = f2bf(f.y); o.z = f2bf(f.z); o.w = f2bf(f.w);
  ((ushort4*)dst)[off] = o;
}

// ---------------- merged Q/K/V projection GEMM (one launch, 1536 blocks) ----------------
// which = blockIdx.x>>9 selects {0:Q(scale), 1:K, 2:V(transposed store)}.
// Per-512-group: flat XCD-chunked decode (R11). BK=64. A staged fp32->reg->
// cvt_pk->ds_write (R12); B staged bf16->reg->ds_write (R18). LDS rows padded
// to 72 shorts: read conflicts 16-way -> 2-way.
__global__ __launch_bounds__(256)
void gemm_qkv(const float* __restrict__ Aq, const float* __restrict__ Ak,
              const float* __restrict__ Av,
              const unsigned short* __restrict__ Wq, const unsigned short* __restrict__ Wk,
              const unsigned short* __restrict__ Wv,
              const float* __restrict__ bq, const float* __restrict__ bk,
              const float* __restrict__ bv,
              unsigned short* __restrict__ Qp, unsigned short* __restrict__ Kp,
              unsigned short* __restrict__ Vt,
              int M, int N, int K) {
  constexpr int LDR = 72;                       // padded row, shorts (144B)
  __shared__ unsigned short As[128 * LDR];
  __shared__ unsigned short Bs[128 * LDR];
  const int which = blockIdx.x >> 9;           // 0..2
  const int bid = blockIdx.x & 511;
  const float* Af = (which == 0) ? Aq : (which == 1) ? Ak : Av;
  const unsigned short* Bw = (which == 0) ? Wq : (which == 1) ? Wk : Wv;
  const float* bias = (which == 0) ? bq : (which == 1) ? bk : bv;

  const int tid = threadIdx.x;
  const int lane = tid & 63;
  const int w = tid >> 6;
  const int wm = (w >> 1) * 64;
  const int wn = (w & 1) * 64;
  const int xcd = bid & 7, jj = bid >> 3;
  const int m0 = (xcd * 8 + (jj >> 3)) * 128;
  const int n0 = (jj & 7) * 128;
  const int l15 = lane & 15, l4 = lane >> 4;

  f32x4 acc[4][4] = {};

  for (int k0 = 0; k0 < K; k0 += 64) {
    // issue all global loads BEFORE the barrier (no LDS hazard; latency hidden)
    float4 av[4][2];
    bf16x8 bst[4];
#pragma unroll
    for (int q = 0; q < 4; ++q) {
      const int c = q * 256 + tid;
      const int row = c >> 3, kc = (c & 7) * 8;
      const float4* ap = (const float4*)(Af + (size_t)(m0 + row) * K + k0 + kc);
      av[q][0] = ap[0];
      av[q][1] = ap[1];
      bst[q] = *(const bf16x8*)(Bw + (size_t)(n0 + row) * K + k0 + kc);
    }
    __syncthreads();  // previous tile's LDS reads done
#pragma unroll
    for (int q = 0; q < 4; ++q) {
      const int c = q * 256 + tid;
      const int row = c >> 3, kc = (c & 7) * 8;
      union { bf16x8 v; unsigned u[4]; } p;
      p.u[0] = cvtpk_bf16(av[q][0].x, av[q][0].y);
      p.u[1] = cvtpk_bf16(av[q][0].z, av[q][0].w);
      p.u[2] = cvtpk_bf16(av[q][1].x, av[q][1].y);
      p.u[3] = cvtpk_bf16(av[q][1].z, av[q][1].w);
      *(bf16x8*)&As[row * LDR + kc] = p.v;
      *(bf16x8*)&Bs[row * LDR + kc] = bst[q];
    }
    __syncthreads();  // publish LDS writes

#pragma unroll
    for (int kk = 0; kk < 2; ++kk) {
      bf16x8 af[4], bfr[4];
#pragma unroll
      for (int m = 0; m < 4; ++m)
        af[m] = *(const bf16x8*)&As[(wm + m * 16 + l15) * LDR + kk * 32 + l4 * 8];
#pragma unroll
      for (int n = 0; n < 4; ++n)
        bfr[n] = *(const bf16x8*)&Bs[(wn + n * 16 + l15) * LDR + kk * 32 + l4 * 8];
#pragma unroll
      for (int m = 0; m < 4; ++m)
#pragma unroll
        for (int n = 0; n < 4; ++n)
          acc[m][n] = __builtin_amdgcn_mfma_f32_16x16x32_bf16(af[m], bfr[n], acc[m][n], 0, 0, 0);
    }
  }

  const int crow = l4 * 4;
#pragma unroll
  for (int m = 0; m < 4; ++m) {
#pragma unroll
    for (int n = 0; n < 4; ++n) {
      const int col = n0 + wn + n * 16 + l15;
      const float bv_ = bias[col];
      if (which == 2) {
        // V: write transposed Vt[(b*16+h)*64+d][s], 4 consecutive s per 8B store
        constexpr int SS = 2048;
        const int rowb = m0 + wm + m * 16 + crow;      // multiple of 4
        const int b_ = rowb >> 11, s_ = rowb & (SS - 1);
        const int vrow = ((b_ << 4) + (col >> 6)) * 64 + (col & 63);
        uint2 pk;
        pk.x = cvtpk_bf16(acc[m][n][0] + bv_, acc[m][n][1] + bv_);
        pk.y = cvtpk_bf16(acc[m][n][2] + bv_, acc[m][n][3] + bv_);
        *(uint2*)&Vt[(size_t)vrow * SS + s_] = pk;
      } else {
        unsigned short* Cb = (which == 0) ? Qp : Kp;
        const float sc = (which == 0) ? 0.125f * 1.44269504f : 1.0f;
#pragma unroll
        for (int j = 0; j < 4; ++j) {
          const int row = m0 + wm + m * 16 + crow + j;
          Cb[(size_t)row * N + col] = f2bf((acc[m][n][j] + bv_) * sc);
        }
      }
    }
  }
}

// ---------------- output projection GEMM (bf16 A, fp32 out; padded LDS) ----------------
__global__ __launch_bounds__(256)
void gemm_out(const unsigned short* __restrict__ Ab,
              const unsigned short* __restrict__ Bw,
              const float* __restrict__ bias,
              float* __restrict__ Cf,
              int M, int N, int K) {
  constexpr int LDR = 72;
  __shared__ unsigned short As[128 * LDR];
  __shared__ unsigned short Bs[128 * LDR];
  const int tid = threadIdx.x;
  const int lane = tid & 63;
  const int w = tid >> 6;
  const int wm = (w >> 1) * 64;
  const int wn = (w & 1) * 64;
  const int bid = blockIdx.x;
  const int xcd = bid & 7, jj = bid >> 3;
  const int m0 = (xcd * 8 + (jj >> 3)) * 128;
  const int n0 = (jj & 7) * 128;
  const int l15 = lane & 15, l4 = lane >> 4;

  f32x4 acc[4][4] = {};

  for (int k0 = 0; k0 < K; k0 += 64) {
    bf16x8 ast[4], bst[4];
#pragma unroll
    for (int q = 0; q < 4; ++q) {
      const int c = q * 256 + tid;
      const int row = c >> 3, kc = (c & 7) * 8;
      ast[q] = *(const bf16x8*)(Ab + (size_t)(m0 + row) * K + k0 + kc);
      bst[q] = *(const bf16x8*)(Bw + (size_t)(n0 + row) * K + k0 + kc);
    }
    __syncthreads();
#pragma unroll
    for (int q = 0; q < 4; ++q) {
      const int c = q * 256 + tid;
      const int row = c >> 3, kc = (c & 7) * 8;
      *(bf16x8*)&As[row * LDR + kc] = ast[q];
      *(bf16x8*)&Bs[row * LDR + kc] = bst[q];
    }
    __syncthreads();

#pragma unroll
    for (int kk = 0; kk < 2; ++kk) {
      bf16x8 af[4], bfr[4];
#pragma unroll
      for (int m = 0; m < 4; ++m)
        af[m] = *(const bf16x8*)&As[(wm + m * 16 + l15) * LDR + kk * 32 + l4 * 8];
#pragma unroll
      for (int n = 0; n < 4; ++n)
        bfr[n] = *(const bf16x8*)&Bs[(wn + n * 16 + l15) * LDR + kk * 32 + l4 * 8];
#pragma unroll
      for (int m = 0; m < 4; ++m)
#pragma unroll
        for (int n = 0; n < 4; ++n)
          acc[m][n] = __builtin_amdgcn_mfma_f32_16x16x32_bf16(af[m], bfr[n], acc[m][n], 0, 0, 0);
    }
  }

  const int crow = l4 * 4;
#pragma unroll
  for (int m = 0; m < 4; ++m) {
#pragma unroll
    for (int n = 0; n < 4; ++n) {
      const int col = n0 + wn + n * 16 + l15;
      const float bv_ = bias[col];
#pragma unroll
      for (int j = 0; j < 4; ++j) {
        const int row = m0 + wm + m * 16 + crow + j;
        Cf[(size_t)row * N + col] = acc[m][n][j] + bv_;
      }
    }
  }
}

// ---------------- flash attention, causal, cooperative 4-wave blocks ----------------
// FROZEN: byte-identical to R15 (g = 15 - bid>>6; GTBL reverted per R17 A/B).
__global__ __launch_bounds__(256)
void attn_fwd32b(const unsigned short* __restrict__ Qp,   // [B*S,1024] bf16 (scaled)
                 const unsigned short* __restrict__ Kp,   // [B*S,1024] bf16
                 const unsigned short* __restrict__ Vt,   // [(b*16+h)*64+d, S] bf16
                 unsigned short* __restrict__ Xo) {       // [B*S,1024] bf16
  constexpr int S = 2048, Dm = 1024;
  const int bh = blockIdx.x & 63;
  const int g  = 15 - (int)(blockIdx.x >> 6);   // longest blocks first
  const int b = bh >> 4, h = bh & 15;
  const int w = threadIdx.x >> 6;
  const int lane = threadIdx.x & 63;
  const int l31 = lane & 31, hi = lane >> 5;
  const int qb = 4 * g + w;
  const int qrow = qb * 32 + l31;
  const int ntw = qb + 1;          // this wave's KV tiles; tile ntw-1 masked
  const int NT = 4 * g + 4;        // uniform block trip count (even)

  // Q B-frags: col=q=l31, k(d)=c*16+hi*8
  const unsigned short* qptr = Qp + (size_t)(b * S + qrow) * Dm + h * 64 + hi * 8;
  bf16x8 qf[4];
#pragma unroll
  for (int c = 0; c < 4; ++c) qf[c] = *(const bf16x8*)(qptr + c * 16);

  const unsigned short* kbase = Kp + (size_t)(b * S) * Dm + h * 64 + hi * 8;
  const unsigned short* vr0 = Vt + (size_t)(bh * 64 + l31) * S + hi * 8;
  const unsigned short* vr1 = vr0 + (size_t)32 * S;

  f32x16 ot0 = {}, ot1 = {};   // O^T: rows d (0-31 / 32-63), col q=l31
  float m = -1e30f, l = 0.f;

  auto loadK = [&](bf16x8 (&kr)[4], int t) {
    const unsigned short* krow = kbase + (size_t)(t * 32 + l31) * Dm;
#pragma unroll
    for (int c = 0; c < 4; ++c) kr[c] = *(const bf16x8*)(krow + c * 16);
  };

  auto body = [&](bf16x8 (&kr)[4], int t) {
    const int kv0 = t * 32;
    // V loads issued early; consumed after softmax
    const bf16x8 vf0a = *(const bf16x8*)(vr0 + kv0);
    const bf16x8 vf0b = *(const bf16x8*)(vr0 + kv0 + 16);
    const bf16x8 vf1a = *(const bf16x8*)(vr1 + kv0);
    const bf16x8 vf1b = *(const bf16x8*)(vr1 + kv0 + 16);
    // S^T = K · Q  (rows kv, col q)
    f32x16 ts = {};
    __builtin_amdgcn_s_setprio(1);
#pragma unroll
    for (int c = 0; c < 4; ++c) ts = mfma32(kr[c], qf[c], ts);
    __builtin_amdgcn_s_setprio(0);
    if (t == ntw - 1) {   // diagonal tile
#pragma unroll
      for (int r = 0; r < 16; ++r) {
        const int kvp = kv0 + (r & 3) + 8 * (r >> 2) + 4 * hi;
        if (kvp > qrow) ts[r] = -1e9f;
      }
    }
    // row max: lane-local + 1 cross-half shfl
    float pmax = ts[0];
#pragma unroll
    for (int r = 1; r < 16; ++r) pmax = fmaxf(pmax, ts[r]);
    pmax = fmaxf(pmax, __shfl_xor(pmax, 32));
    // deferred rescale (T13; log2 units)
    if (__any(pmax > m + 11.5f)) {
      const float mn = (pmax > m + 11.5f) ? pmax : m;
      const float fct = __builtin_amdgcn_exp2f(m - mn);
      m = mn; l *= fct;
#pragma unroll
      for (int r = 0; r < 16; ++r) { ot0[r] *= fct; ot1[r] *= fct; }
    }
    // p = 2^(s-m), row-sum
    float p[16], ls = 0.f;
#pragma unroll
    for (int r = 0; r < 16; ++r) {
      p[r] = __builtin_amdgcn_exp2f(ts[r] - m);
      ls += p[r];
    }
    ls += __shfl_xor(ls, 32);
    l += ls;
    // pack bf16 pairs + cross-half exchange -> P^T B-frags (k=kv)
    unsigned ua[8];
#pragma unroll
    for (int i = 0; i < 8; ++i) ua[i] = cvtpk_bf16(p[2 * i], p[2 * i + 1]);
    union FR { bf16x8 v; unsigned u[4]; } fr0, fr1;
    {
      unsigned sa = hi ? ua[0] : ua[2], sb = hi ? ua[1] : ua[3];
      unsigned xa = __shfl_xor(sa, 32), xb = __shfl_xor(sb, 32);
      fr0.u[0] = hi ? xa : ua[0]; fr0.u[1] = hi ? xb : ua[1];
      fr0.u[2] = hi ? ua[2] : xa; fr0.u[3] = hi ? ua[3] : xb;
      unsigned sc = hi ? ua[4] : ua[6], sd = hi ? ua[5] : ua[7];
      unsigned xc = __shfl_xor(sc, 32), xd = __shfl_xor(sd, 32);
      fr1.u[0] = hi ? xc : ua[4]; fr1.u[1] = hi ? xd : ua[5];
      fr1.u[2] = hi ? ua[6] : xc; fr1.u[3] = hi ? ua[7] : xd;
    }
    // O^T += V^T · P^T
    __builtin_amdgcn_s_setprio(1);
    ot0 = mfma32(vf0a, fr0.v, ot0);
    ot0 = mfma32(vf0b, fr1.v, ot0);
    ot1 = mfma32(vf1a, fr0.v, ot1);
    ot1 = mfma32(vf1b, fr1.v, ot1);
    __builtin_amdgcn_s_setprio(0);
  };

  // ping-pong K prefetch; identical loads across the 4 waves (L1-shared).
  bf16x8 kA[4], kB[4];
  loadK(kA, 0);
  for (int t = 0; t < NT; t += 2) {
    loadK(kB, t + 1);
    if (t < ntw) body(kA, t);
    __builtin_amdgcn_s_barrier();
    const int t2 = (t + 2 < NT) ? (t + 2) : (NT - 1);  // clamped (redundant on last)
    loadK(kA, t2);
    if (t + 1 < ntw) body(kB, t + 1);
    __builtin_amdgcn_s_barrier();
  }

  // epilogue: normalize (lane-local l), pack pairs, 8B stores
  const float inv = 1.f / l;
  unsigned short* orow = Xo + (size_t)(b * S + qrow) * Dm + h * 64;
#pragma unroll
  for (int rq = 0; rq < 4; ++rq) {
    uint2 pr;
    pr.x = cvtpk_bf16(ot0[4 * rq + 0] * inv, ot0[4 * rq + 1] * inv);
    pr.y = cvtpk_bf16(ot0[4 * rq + 2] * inv, ot0[4 * rq + 3] * inv);
    *(uint2*)(orow + 8 * rq + 4 * hi) = pr;
    uint2 pr1;
    pr1.x = cvtpk_bf16(ot1[4 * rq + 0] * inv, ot1[4 * rq + 1] * inv);
    pr1.y = cvtpk_bf16(ot1[4 * rq + 2] * inv, ot1[4 * rq + 3] * inv);
    *(uint2*)(orow + 32 + 8 * rq + 4 * hi) = pr1;
  }
}

// ---------------- launch ----------------
extern "C" void kernel_launch(void* const* d_in, const int* in_sizes, int n_in,
                              void* d_out, int out_size, void* d_ws, size_t ws_size,
                              hipStream_t stream) {
  const float* query = (const float*)d_in[0];
  const float* key   = (const float*)d_in[1];
  const float* value = (const float*)d_in[2];
  const float* Wq = (const float*)d_in[4];
  const float* bq = (const float*)d_in[5];
  const float* Wk = (const float*)d_in[6];
  const float* bk = (const float*)d_in[7];
  const float* Wv = (const float*)d_in[8];
  const float* bv = (const float*)d_in[9];
  const float* Wo = (const float*)d_in[10];
  const float* bo = (const float*)d_in[11];

  constexpr int B = 4, S = 2048, D = 1024;
  constexpr int M = B * S;
  const size_t MB = 1024u * 1024u;
  uint8_t* ws = (uint8_t*)d_ws;

  unsigned short* Wqb = (unsigned short*)(ws + 48 * MB);
  unsigned short* Wkb = (unsigned short*)(ws + 50 * MB);
  unsigned short* Wvb = (unsigned short*)(ws + 52 * MB);
  unsigned short* Wob = (unsigned short*)(ws + 54 * MB);
  unsigned short* Qp  = (unsigned short*)(ws + 56 * MB);
  unsigned short* Kp  = (unsigned short*)(ws + 72 * MB);
  unsigned short* Vt  = (unsigned short*)(ws + 32 * MB);
  unsigned short* Xat = (unsigned short*)(ws + 16 * MB);

  // weights-only cast: 4*W4 float4 units
  constexpr int W4 = D * D / 4;
  cast_w<<<4 * W4 / 256, 256, 0, stream>>>(Wq, Wk, Wv, Wo, Wqb, Wkb, Wvb, Wob);

  // merged Q/K/V projections: one 1536-block launch, BK=64, padded LDS
  gemm_qkv<<<1536, 256, 0, stream>>>(query, key, value, Wqb, Wkb, Wvb,
                                     bq, bk, bv, Qp, Kp, Vt, M, D, D);

  attn_fwd32b<<<1024, 256, 0, stream>>>(Qp, Kp, Vt, Xat);

  // output projection: A already bf16, fp32 out, BK=64, padded LDS
  gemm_out<<<512, 256, 0, stream>>>(Xat, Wob, bo, (float*)d_out, M, D, D);
}